// Round 18
// baseline (129.519 us; speedup 1.0000x reference)
//
#include <hip/hip_runtime.h>
#include <hip/hip_bf16.h>

// out[b,h,w,dy*9+dx] = leaky_relu( mean_c( prv[b,h,w,c] * nxt[b,h+dy-4,w+dx-4,c] ), 0.1 )
// R18: R14 WITHOUT the k-phase stagger (stagger broke L2/L3 temporal sharing:
// FETCH 122->269MB). Verified 16x16 banded-MFMA core; A (prv) direct-to-register
// (wave-private row); B (nxt) double-buffered bf16 LDS; TWO phases of B register
// prefetch in flight -> phase-start ds_write waits on 2-phase-old loads (full-phase
// latency cover); one lgkm-only barrier per phase.

#define B_ 8
#define H_ 128
#define W_ 128
#define C_ 192
#define ND 9
#define NDISP 81
#define HT 16           // tile rows
#define WT 16           // tile cols
#define KS 32           // channels per k-step
#define NK 6            // 192/32
#define BROWS 24        // staged nxt rows
#define BCOLS 24        // staged nxt cols
#define BPIX (BROWS * BCOLS)   // 576
#define BSTR 577               // odd 8B-slot stride (granule-major)
#define BSLOTS (8 * BSTR)      // 4616
#define NSB 5                  // B granule-slots per thread; slot 4 covers tid<512

typedef short short8 __attribute__((ext_vector_type(8)));
typedef short short4_t __attribute__((ext_vector_type(4)));
typedef float f32x4 __attribute__((ext_vector_type(4)));

static __device__ __forceinline__ short bf1(float f) {
    __hip_bfloat16 h = __float2bfloat16(f);   // pairs fuse to v_cvt_pk_bf16_f32
    return __builtin_bit_cast(short, h);
}

static __device__ __forceinline__ short4_t cvt4(float4 v) {
    short4_t r;
    r[0] = bf1(v.x); r[1] = bf1(v.y); r[2] = bf1(v.z); r[3] = bf1(v.w);
    return r;
}

static __device__ __forceinline__ short8 cat(short4_t u, short4_t v) {
    return __builtin_shufflevector(u, v, 0, 1, 2, 3, 4, 5, 6, 7);
}

// LDS-fence + barrier WITHOUT vmcnt drain: outstanding global loads stay in flight.
static __device__ __forceinline__ void barrier_lgkm() {
    asm volatile("s_waitcnt lgkmcnt(0)\n\ts_barrier" ::: "memory");
}

__global__ __launch_bounds__(1024, 4)
void cv_mfma(const float* __restrict__ prv, const float* __restrict__ nxt,
             float* __restrict__ out) {
    __shared__ short4_t sm[2][BSLOTS];   // 2 x 36.9 KB (B only)

    const int tid = threadIdx.x;
    const int w0 = blockIdx.x * WT;
    const int h0 = blockIdx.y * HT;
    const int b  = blockIdx.z;

    const int lane = tid & 63;
    const int wid  = tid >> 6;      // 0..15: wave owns output row h0+wid
    const int lq = lane & 15;
    const int lc = lane >> 4;

    const int tp = tid >> 3;        // 0..127: B pixel sub-index for staging
    const int c8 = tid & 7;         // 0..7: 4-channel granule within k-step

    // ---- B staging offsets (k-step adds ks*KS)
    int boff[NSB];
    unsigned bmask = 0;
#pragma unroll
    for (int i = 0; i < NSB; ++i) {
        const int p = tp + 128 * i;        // 0..639; slot 4 valid only p<576
        const int row = p / BCOLS;
        const int col = p - row * BCOLS;
        const int gh = h0 - 4 + row;
        const int gw = w0 - 4 + col;
        const bool inb = (p < BPIX) && ((unsigned)gh < (unsigned)H_) && ((unsigned)gw < (unsigned)W_);
        if (inb) bmask |= (1u << i);
        boff[i] = ((b * H_ + (inb ? gh : 0)) * W_ + (inb ? gw : 0)) * C_ + c8 * 4;
    }
    const bool wr4 = (tid < 512);   // slot-4 write coverage, wave-uniform

    // ---- A: direct per-wave frag address (thread reads pixel (wid, lq), ch 8*lc)
    const int aoff = ((b * H_ + h0 + wid) * W_ + w0 + lq) * C_ + lc * 8;

    // ---- prologue: A(0) + B(0) + B(1) in flight (no stagger: all blocks at ks=0)
    float4 xa0, xa1;
    float4 xb0[NSB], xb1[NSB];
    {
        xa0 = *(const float4*)(prv + aoff);
        xa1 = *(const float4*)(prv + aoff + 4);
#pragma unroll
        for (int i = 0; i < NSB; ++i) {
            xb0[i] = make_float4(0.f, 0.f, 0.f, 0.f);
            if (bmask & (1u << i)) xb0[i] = *(const float4*)(nxt + boff[i]);
        }
#pragma unroll
        for (int i = 0; i < NSB; ++i) {
            xb1[i] = make_float4(0.f, 0.f, 0.f, 0.f);
            if (bmask & (1u << i)) xb1[i] = *(const float4*)(nxt + boff[i] + KS);
        }
    }

    f32x4 acc[ND][2];
#pragma unroll
    for (int d = 0; d < ND; ++d) {
        acc[d][0] = (f32x4){0.f, 0.f, 0.f, 0.f};
        acc[d][1] = (f32x4){0.f, 0.f, 0.f, 0.f};
    }

    // ---- phases, fully unrolled; XB parity array is write-source (k) and reload
    // dest (k+2); its ds_write waits on loads issued 2 phases ago (full cover).
#define PHASE(IT, XB)                                                              \
    {                                                                              \
        short4_t* sB = sm[IT & 1];                                                 \
        _Pragma("unroll")                                                          \
        for (int i = 0; i < NSB - 1; ++i)                                          \
            sB[c8 * BSTR + tp + 128 * i] = cvt4(XB[i]);                            \
        if (wr4) sB[c8 * BSTR + tp + 512] = cvt4(XB[NSB - 1]);                     \
        const short8 afrag = cat(cvt4(xa0), cvt4(xa1));                            \
        if (IT + 1 < NK) { /* issue A(IT+1) */                                     \
            const int cn = (IT + 1) * KS;                                          \
            xa0 = *(const float4*)(prv + aoff + cn);                               \
            xa1 = *(const float4*)(prv + aoff + cn + 4);                           \
        }                                                                          \
        if (IT + 2 < NK) { /* issue B(IT+2); in flight for 2 phases */             \
            const int cb = (IT + 2) * KS;                                          \
            _Pragma("unroll")                                                      \
            for (int i = 0; i < NSB; ++i) {                                        \
                if (bmask & (1u << i)) XB[i] = *(const float4*)(nxt + boff[i] + cb); \
            }                                                                      \
        }                                                                          \
        barrier_lgkm();                                                            \
        _Pragma("unroll")                                                          \
        for (int dy = 0; dy < ND; ++dy) {                                          \
            const int pB = (wid + dy) * BCOLS + lq;                                \
            const short8 b0v = cat(sB[2 * lc * BSTR + pB], sB[(2 * lc + 1) * BSTR + pB]); \
            const short8 b1v = cat(sB[2 * lc * BSTR + pB + 8], sB[(2 * lc + 1) * BSTR + pB + 8]); \
            acc[dy][0] = __builtin_amdgcn_mfma_f32_16x16x32_bf16(afrag, b0v, acc[dy][0], 0, 0, 0); \
            acc[dy][1] = __builtin_amdgcn_mfma_f32_16x16x32_bf16(afrag, b1v, acc[dy][1], 0, 0, 0); \
        }                                                                          \
    }

    PHASE(0, xb0)
    PHASE(1, xb1)
    PHASE(2, xb0)
    PHASE(3, xb1)
    PHASE(4, xb0)
    PHASE(5, xb1)
#undef PHASE

    // ---- epilogue (R5/R12/R13-verified): D col=lane&15 (q), D row=4*lc+rg (rD=w-pos).
    // rows rD<8 from tile0 (dx=q-rD), rD>=8 from tile1 (dx=q-rD+8); exclusive+complete.
    const float inv = 1.0f / (float)C_;
    const int h = h0 + wid;
    if (lc < 2) {
#pragma unroll
        for (int rg = 0; rg < 4; ++rg) {
            const int r = 4 * lc + rg;
            const int dx = lq - r;
            if (dx >= 0 && dx <= 8) {
                float* o = out + (size_t)((b * H_ + h) * W_ + w0 + r) * NDISP + dx;
#pragma unroll
                for (int dy = 0; dy < ND; ++dy) {
                    const float v = acc[dy][0][rg] * inv;
                    o[dy * ND] = v >= 0.f ? v : 0.1f * v;
                }
            }
        }
    } else {
#pragma unroll
        for (int rg = 0; rg < 4; ++rg) {
            const int r = 4 * lc + rg;       // 8..15
            const int dx = lq - r + 8;
            if (dx >= 0 && dx <= 8) {
                float* o = out + (size_t)((b * H_ + h) * W_ + w0 + r) * NDISP + dx;
#pragma unroll
                for (int dy = 0; dy < ND; ++dy) {
                    const float v = acc[dy][1][rg] * inv;
                    o[dy * ND] = v >= 0.f ? v : 0.1f * v;
                }
            }
        }
    }
}

extern "C" void kernel_launch(void* const* d_in, const int* in_sizes, int n_in,
                              void* d_out, int out_size, void* d_ws, size_t ws_size,
                              hipStream_t stream) {
    const float* prv = (const float*)d_in[0];
    const float* nxt = (const float*)d_in[1];
    float* out = (float*)d_out;

    dim3 grid(W_ / WT, H_ / HT, B_);   // (8, 8, 8) = 512 blocks x 1024 threads
    cv_mfma<<<grid, 1024, 0, stream>>>(prv, nxt, out);
}

// Round 19
// 110.375 us; speedup vs baseline: 1.1735x; 1.1735x over previous
//
#include <hip/hip_runtime.h>
#include <hip/hip_bf16.h>

// out[b,h,w,dy*9+dx] = leaky_relu( mean_c( prv[b,h,w,c] * nxt[b,h+dy-4,w+dx-4,c] ), 0.1 )
// R19: co-residency test. R12's exact spill-free schedule (single LDS buffer,
// stage -> barrier -> compute, 2 barriers/phase, NO deep prefetch) on an 8x16 tile:
// 512 thr / 8 waves / wave = 1 row; acc 72 f32 -> ~115 VGPR; LDS 33 KB single-buf
// => 2 independent blocks (barrier groups) per CU. R18's lesson: deep reg prefetch
// spills (WRITE 223MB); R10 vs R12: co-resident blocks set the load-issue rate.

#define B_ 8
#define H_ 128
#define W_ 128
#define C_ 192
#define ND 9
#define NDISP 81
#define HT 8            // tile rows (one per wave)
#define WT 16           // tile cols
#define KS 32           // channels per k-step
#define NK 6            // 192/32
#define BROWS 16        // HT+8 staged nxt rows
#define BCOLS 24        // WT+8 staged nxt cols
#define APIX (HT * WT)         // 128
#define BPIX (BROWS * BCOLS)   // 384
#define ASTR 129               // odd 8B-slot stride (granule-major) for A
#define BSTR 385               // odd stride for B
#define NSA 2                  // A granule-slots per thread (128*8/512), exact
#define NSB 6                  // B granule-slots per thread (384*8/512), exact

typedef short short8 __attribute__((ext_vector_type(8)));
typedef short short4_t __attribute__((ext_vector_type(4)));
typedef float f32x4 __attribute__((ext_vector_type(4)));

static __device__ __forceinline__ short bf1(float f) {
    __hip_bfloat16 h = __float2bfloat16(f);   // pairs fuse to v_cvt_pk_bf16_f32
    return __builtin_bit_cast(short, h);
}

static __device__ __forceinline__ short4_t cvt4(float4 v) {
    short4_t r;
    r[0] = bf1(v.x); r[1] = bf1(v.y); r[2] = bf1(v.z); r[3] = bf1(v.w);
    return r;
}

static __device__ __forceinline__ short8 cat(short4_t u, short4_t v) {
    return __builtin_shufflevector(u, v, 0, 1, 2, 3, 4, 5, 6, 7);
}

__global__ __launch_bounds__(512, 4)
void cv_mfma(const float* __restrict__ prv, const float* __restrict__ nxt,
             float* __restrict__ out) {
    // single buffer: A (8 granules x 128 px) + B (8 x 384), granule-major odd stride
    __shared__ short4_t sm[8 * ASTR + 8 * BSTR];   // 4112 slots = 32.9 KB
    short4_t* sA = sm;
    short4_t* sB = sm + 8 * ASTR;

    const int tid = threadIdx.x;
    const int w0 = blockIdx.x * WT;
    const int h0 = blockIdx.y * HT;
    const int b  = blockIdx.z;

    const int lane = tid & 63;
    const int wid  = tid >> 6;      // 0..7: wave owns output row h0+wid
    const int lq = lane & 15;
    const int lc = lane >> 4;

    const int tp = tid >> 3;        // 0..63: pixel sub-index for staging
    const int c8 = tid & 7;         // 0..7: 4-channel granule within k-step

    // ---- hoisted global element-offsets (k-step adds ks*KS)
    int aoff[NSA];
#pragma unroll
    for (int i = 0; i < NSA; ++i) {
        const int p = tp + 64 * i;        // 0..127
        const int r = p >> 4;
        const int pc = p & 15;
        aoff[i] = ((b * H_ + h0 + r) * W_ + w0 + pc) * C_ + c8 * 4;
    }
    int boff[NSB];
    unsigned bmask = 0;
#pragma unroll
    for (int i = 0; i < NSB; ++i) {
        const int p = tp + 64 * i;        // 0..383
        const int row = p / BCOLS;
        const int col = p - row * BCOLS;
        const int gh = h0 - 4 + row;
        const int gw = w0 - 4 + col;
        const bool inb = ((unsigned)gh < (unsigned)H_) && ((unsigned)gw < (unsigned)W_);
        if (inb) bmask |= (1u << i);
        boff[i] = ((b * H_ + (inb ? gh : 0)) * W_ + (inb ? gw : 0)) * C_ + c8 * 4;
    }

    f32x4 acc[ND][2];
#pragma unroll
    for (int d = 0; d < ND; ++d) {
        acc[d][0] = (f32x4){0.f, 0.f, 0.f, 0.f};
        acc[d][1] = (f32x4){0.f, 0.f, 0.f, 0.f};
    }

    for (int ks = 0; ks < NK; ++ks) {
        if (ks) __syncthreads();
        const int co = ks * KS;

        // ---- stage A (2 slots) + B (6 slots), coalesced dwordx4, batched issue
        {
            float4 va[NSA];
#pragma unroll
            for (int i = 0; i < NSA; ++i)
                va[i] = *(const float4*)(prv + aoff[i] + co);
            float4 vb[NSB];
#pragma unroll
            for (int i = 0; i < NSB; ++i) {
                vb[i] = make_float4(0.f, 0.f, 0.f, 0.f);
                if (bmask & (1u << i)) vb[i] = *(const float4*)(nxt + boff[i] + co);
            }
#pragma unroll
            for (int i = 0; i < NSA; ++i)
                sA[c8 * ASTR + tp + 64 * i] = cvt4(va[i]);
#pragma unroll
            for (int i = 0; i < NSB; ++i)
                sB[c8 * BSTR + tp + 64 * i] = cvt4(vb[i]);
        }
        __syncthreads();

        // ---- compute: wave's row vs 9 dy x 2 overlapping col-tiles
        const int pA = wid * WT + lq;
        const short8 a = cat(sA[2 * lc * ASTR + pA], sA[(2 * lc + 1) * ASTR + pA]);
#pragma unroll
        for (int dy = 0; dy < ND; ++dy) {
            const int pB = (wid + dy) * BCOLS + lq;
            const short8 b0 = cat(sB[2 * lc * BSTR + pB],     sB[(2 * lc + 1) * BSTR + pB]);
            const short8 b1 = cat(sB[2 * lc * BSTR + pB + 8], sB[(2 * lc + 1) * BSTR + pB + 8]);
            acc[dy][0] = __builtin_amdgcn_mfma_f32_16x16x32_bf16(a, b0, acc[dy][0], 0, 0, 0);
            acc[dy][1] = __builtin_amdgcn_mfma_f32_16x16x32_bf16(a, b1, acc[dy][1], 0, 0, 0);
        }
    }

    // ---- epilogue (R5/R10/R12-verified): D col=lane&15 (q), D row=4*lc+rg (rD=w-pos).
    // rows rD<8 from tile0 (dx=q-rD), rD>=8 from tile1 (dx=q-rD+8); exclusive+complete.
    const float inv = 1.0f / (float)C_;
    const int h = h0 + wid;
    if (lc < 2) {
#pragma unroll
        for (int rg = 0; rg < 4; ++rg) {
            const int r = 4 * lc + rg;
            const int dx = lq - r;
            if (dx >= 0 && dx <= 8) {
                float* o = out + (size_t)((b * H_ + h) * W_ + w0 + r) * NDISP + dx;
#pragma unroll
                for (int dy = 0; dy < ND; ++dy) {
                    const float v = acc[dy][0][rg] * inv;
                    o[dy * ND] = v >= 0.f ? v : 0.1f * v;
                }
            }
        }
    } else {
#pragma unroll
        for (int rg = 0; rg < 4; ++rg) {
            const int r = 4 * lc + rg;       // 8..15
            const int dx = lq - r + 8;
            if (dx >= 0 && dx <= 8) {
                float* o = out + (size_t)((b * H_ + h) * W_ + w0 + r) * NDISP + dx;
#pragma unroll
                for (int dy = 0; dy < ND; ++dy) {
                    const float v = acc[dy][1][rg] * inv;
                    o[dy * ND] = v >= 0.f ? v : 0.1f * v;
                }
            }
        }
    }
}

extern "C" void kernel_launch(void* const* d_in, const int* in_sizes, int n_in,
                              void* d_out, int out_size, void* d_ws, size_t ws_size,
                              hipStream_t stream) {
    const float* prv = (const float*)d_in[0];
    const float* nxt = (const float*)d_in[1];
    float* out = (float*)d_out;

    dim3 grid(W_ / WT, H_ / HT, B_);   // (8, 16, 8) = 1024 blocks x 512 threads
    cv_mfma<<<grid, 512, 0, stream>>>(prv, nxt, out);
}

// Round 20
// 96.711 us; speedup vs baseline: 1.3392x; 1.1413x over previous
//
#include <hip/hip_runtime.h>
#include <hip/hip_bf16.h>

// out[b,h,w,dy*9+dx] = leaky_relu( mean_c( prv[b,h,w,c] * nxt[b,h+dy-4,w+dx-4,c] ), 0.1 )
// R20: spill-free co-residency test. R19's 8x16-tile single-buffer schedule with
// staging register pressure halved: A written immediately, B staged in two
// sequential batches of 3 float4 (peak 12 live stage regs). Target: <=128 VGPR
// under __launch_bounds__(512,4) -> 2 independent 8-wave blocks per CU.

#define B_ 8
#define H_ 128
#define W_ 128
#define C_ 192
#define ND 9
#define NDISP 81
#define HT 8            // tile rows (one per wave)
#define WT 16           // tile cols
#define KS 32           // channels per k-step
#define NK 6            // 192/32
#define BROWS 16        // HT+8 staged nxt rows
#define BCOLS 24        // WT+8 staged nxt cols
#define APIX (HT * WT)         // 128
#define BPIX (BROWS * BCOLS)   // 384
#define ASTR 129               // odd 8B-slot stride (granule-major) for A
#define BSTR 385               // odd stride for B
#define NSA 2                  // A granule-slots per thread (exact)
#define NSB 6                  // B granule-slots per thread (exact)

typedef short short8 __attribute__((ext_vector_type(8)));
typedef short short4_t __attribute__((ext_vector_type(4)));
typedef float f32x4 __attribute__((ext_vector_type(4)));

static __device__ __forceinline__ short bf1(float f) {
    __hip_bfloat16 h = __float2bfloat16(f);   // pairs fuse to v_cvt_pk_bf16_f32
    return __builtin_bit_cast(short, h);
}

static __device__ __forceinline__ short4_t cvt4(float4 v) {
    short4_t r;
    r[0] = bf1(v.x); r[1] = bf1(v.y); r[2] = bf1(v.z); r[3] = bf1(v.w);
    return r;
}

static __device__ __forceinline__ short8 cat(short4_t u, short4_t v) {
    return __builtin_shufflevector(u, v, 0, 1, 2, 3, 4, 5, 6, 7);
}

__global__ __launch_bounds__(512, 4)
void cv_mfma(const float* __restrict__ prv, const float* __restrict__ nxt,
             float* __restrict__ out) {
    // single buffer: A (8 granules x 128 px) + B (8 x 384), granule-major odd stride
    __shared__ short4_t sm[8 * ASTR + 8 * BSTR];   // 4112 slots = 32.9 KB
    short4_t* sA = sm;
    short4_t* sB = sm + 8 * ASTR;

    const int tid = threadIdx.x;
    const int w0 = blockIdx.x * WT;
    const int h0 = blockIdx.y * HT;
    const int b  = blockIdx.z;

    const int lane = tid & 63;
    const int wid  = tid >> 6;      // 0..7: wave owns output row h0+wid
    const int lq = lane & 15;
    const int lc = lane >> 4;

    const int tp = tid >> 3;        // 0..63: pixel sub-index for staging
    const int c8 = tid & 7;         // 0..7: 4-channel granule within k-step

    // ---- hoisted global element-offsets (k-step adds ks*KS)
    int aoff[NSA];
#pragma unroll
    for (int i = 0; i < NSA; ++i) {
        const int p = tp + 64 * i;        // 0..127
        aoff[i] = ((b * H_ + h0 + (p >> 4)) * W_ + w0 + (p & 15)) * C_ + c8 * 4;
    }
    int boff[NSB];
    unsigned bmask = 0;
#pragma unroll
    for (int i = 0; i < NSB; ++i) {
        const int p = tp + 64 * i;        // 0..383
        const int row = p / BCOLS;
        const int col = p - row * BCOLS;
        const int gh = h0 - 4 + row;
        const int gw = w0 - 4 + col;
        const bool inb = ((unsigned)gh < (unsigned)H_) && ((unsigned)gw < (unsigned)W_);
        if (inb) bmask |= (1u << i);
        boff[i] = ((b * H_ + (inb ? gh : 0)) * W_ + (inb ? gw : 0)) * C_ + c8 * 4;
    }

    f32x4 acc[ND][2];
#pragma unroll
    for (int d = 0; d < ND; ++d) {
        acc[d][0] = (f32x4){0.f, 0.f, 0.f, 0.f};
        acc[d][1] = (f32x4){0.f, 0.f, 0.f, 0.f};
    }

    for (int ks = 0; ks < NK; ++ks) {
        if (ks) __syncthreads();
        const int co = ks * KS;

        // ---- stage A (immediate write), then B in two batches of 3: peak 12 live
        // staging regs -> no spill at the 128-VGPR cap.
        {
            float4 va0 = *(const float4*)(prv + aoff[0] + co);
            float4 va1 = *(const float4*)(prv + aoff[1] + co);
            sA[c8 * ASTR + tp]      = cvt4(va0);
            sA[c8 * ASTR + tp + 64] = cvt4(va1);
        }
#pragma unroll
        for (int bt = 0; bt < 2; ++bt) {
            float4 vb[3];
#pragma unroll
            for (int j = 0; j < 3; ++j) {
                const int i = 3 * bt + j;
                vb[j] = make_float4(0.f, 0.f, 0.f, 0.f);
                if (bmask & (1u << i)) vb[j] = *(const float4*)(nxt + boff[i] + co);
            }
#pragma unroll
            for (int j = 0; j < 3; ++j)
                sB[c8 * BSTR + tp + 64 * (3 * bt + j)] = cvt4(vb[j]);
        }
        __syncthreads();

        // ---- compute: wave's row vs 9 dy x 2 overlapping col-tiles
        const int pA = wid * WT + lq;
        const short8 a = cat(sA[2 * lc * ASTR + pA], sA[(2 * lc + 1) * ASTR + pA]);
#pragma unroll
        for (int dy = 0; dy < ND; ++dy) {
            const int pB = (wid + dy) * BCOLS + lq;
            const short8 b0 = cat(sB[2 * lc * BSTR + pB],     sB[(2 * lc + 1) * BSTR + pB]);
            const short8 b1 = cat(sB[2 * lc * BSTR + pB + 8], sB[(2 * lc + 1) * BSTR + pB + 8]);
            acc[dy][0] = __builtin_amdgcn_mfma_f32_16x16x32_bf16(a, b0, acc[dy][0], 0, 0, 0);
            acc[dy][1] = __builtin_amdgcn_mfma_f32_16x16x32_bf16(a, b1, acc[dy][1], 0, 0, 0);
        }
    }

    // ---- epilogue (R5/R10/R12-verified): D col=lane&15 (q), D row=4*lc+rg (rD=w-pos).
    // rows rD<8 from tile0 (dx=q-rD), rD>=8 from tile1 (dx=q-rD+8); exclusive+complete.
    const float inv = 1.0f / (float)C_;
    const int h = h0 + wid;
    if (lc < 2) {
#pragma unroll
        for (int rg = 0; rg < 4; ++rg) {
            const int r = 4 * lc + rg;
            const int dx = lq - r;
            if (dx >= 0 && dx <= 8) {
                float* o = out + (size_t)((b * H_ + h) * W_ + w0 + r) * NDISP + dx;
#pragma unroll
                for (int dy = 0; dy < ND; ++dy) {
                    const float v = acc[dy][0][rg] * inv;
                    o[dy * ND] = v >= 0.f ? v : 0.1f * v;
                }
            }
        }
    } else {
#pragma unroll
        for (int rg = 0; rg < 4; ++rg) {
            const int r = 4 * lc + rg;       // 8..15
            const int dx = lq - r + 8;
            if (dx >= 0 && dx <= 8) {
                float* o = out + (size_t)((b * H_ + h) * W_ + w0 + r) * NDISP + dx;
#pragma unroll
                for (int dy = 0; dy < ND; ++dy) {
                    const float v = acc[dy][1][rg] * inv;
                    o[dy * ND] = v >= 0.f ? v : 0.1f * v;
                }
            }
        }
    }
}

extern "C" void kernel_launch(void* const* d_in, const int* in_sizes, int n_in,
                              void* d_out, int out_size, void* d_ws, size_t ws_size,
                              hipStream_t stream) {
    const float* prv = (const float*)d_in[0];
    const float* nxt = (const float*)d_in[1];
    float* out = (float*)d_out;

    dim3 grid(W_ / WT, H_ / HT, B_);   // (8, 16, 8) = 1024 blocks x 512 threads
    cv_mfma<<<grid, 512, 0, stream>>>(prv, nxt, out);
}